// Round 2
// baseline (53.403 us; speedup 1.0000x reference)
//
#include <hip/hip_runtime.h>
#include <hip/hip_bf16.h>

#define BS_   256
#define NOPS_ 2000
#define NJ_   50
#define NM_   40
#define E_    128
#define H_    128
#define NCOL_ 2001   // 1 + 50*40

using bf16x8 = __attribute__((ext_vector_type(8))) short;
using f32x4  = __attribute__((ext_vector_type(4))) float;

static __device__ __forceinline__ short f2bf(float f) {
  __hip_bfloat16 h = __float2bfloat16(f);
  return __builtin_bit_cast(short, h);
}

__global__ __launch_bounds__(256) void fjsp_fused(
    const float* __restrict__ ops_emb,
    const float* __restrict__ ma_emb,
    const int*   __restrict__ next_op,
    const int*   __restrict__ amask,      // bool input materialized as int32
    const float* __restrict__ dummy,
    const float* __restrict__ W1,
    const float* __restrict__ b1,
    const float* __restrict__ W2,
    const float* __restrict__ b2,
    const float* __restrict__ W3,
    const float* __restrict__ b3,
    float* __restrict__ out)
{
  const int b    = blockIdx.x;
  const int tid  = threadIdx.x;
  const int lane = tid & 63;
  const int wave = tid >> 6;
  const int g    = lane >> 4;   // 0..3  (k-block / D-row group)
  const int lr   = lane & 15;   // 0..15 (A-row / B-col / D-col)

  // padded rows: 136 bf16 = 272B (=17*16B, stride == 4 banks), 132 f32 = 528B
  __shared__ __align__(16) unsigned short embJ[64][136];
  __shared__ __align__(16) unsigned short embM[48][136];
  __shared__ __align__(16) float jp[NJ_][132];
  __shared__ __align__(16) float mp[NM_][132];
  __shared__ float dtmp[128];

  // ---------------- stage embeddings (f32 -> bf16) into LDS ----------------
  {
    const int r = tid >> 2, part = tid & 3;   // 4 threads per row, 32 elems each
    if (r < NJ_) {
      const int idx = next_op[b * NJ_ + r];
      const float4* p = reinterpret_cast<const float4*>(
          ops_emb + ((size_t)b * NOPS_ + idx) * E_) + part * 8;
      #pragma unroll
      for (int q = 0; q < 8; ++q) {
        const float4 v = p[q];
        const int k = part * 32 + q * 4;
        embJ[r][k+0] = (unsigned short)f2bf(v.x);
        embJ[r][k+1] = (unsigned short)f2bf(v.y);
        embJ[r][k+2] = (unsigned short)f2bf(v.z);
        embJ[r][k+3] = (unsigned short)f2bf(v.w);
      }
    } else {
      #pragma unroll
      for (int q = 0; q < 8; ++q) {
        const int k = part * 32 + q * 4;
        embJ[r][k+0] = 0; embJ[r][k+1] = 0; embJ[r][k+2] = 0; embJ[r][k+3] = 0;
      }
    }
    if (tid < 192) {
      if (r < NM_) {
        const float4* p = reinterpret_cast<const float4*>(
            ma_emb + ((size_t)b * NM_ + r) * E_) + part * 8;
        #pragma unroll
        for (int q = 0; q < 8; ++q) {
          const float4 v = p[q];
          const int k = part * 32 + q * 4;
          embM[r][k+0] = (unsigned short)f2bf(v.x);
          embM[r][k+1] = (unsigned short)f2bf(v.y);
          embM[r][k+2] = (unsigned short)f2bf(v.z);
          embM[r][k+3] = (unsigned short)f2bf(v.w);
        }
      } else {
        #pragma unroll
        for (int q = 0; q < 8; ++q) {
          const int k = part * 32 + q * 4;
          embM[r][k+0] = 0; embM[r][k+1] = 0; embM[r][k+2] = 0; embM[r][k+3] = 0;
        }
      }
    }
  }
  __syncthreads();

  // ------- stage A: jp = embJ @ W1[:128] ; mp = embM @ W1[128:] + b1 -------
  #pragma unroll
  for (int phase = 0; phase < 2; ++phase) {
    const int ntiles = phase ? 3 : 4;
    if (wave < ntiles) {
      const int ebase = phase ? E_ : 0;
      const int r0 = wave * 16;
      f32x4 acc[8];
      #pragma unroll
      for (int c = 0; c < 8; ++c) acc[c] = f32x4{0.f, 0.f, 0.f, 0.f};
      #pragma unroll
      for (int f = 0; f < 4; ++f) {
        bf16x8 a;
        if (phase == 0) a = *reinterpret_cast<const bf16x8*>(&embJ[r0 + lr][32*f + 8*g]);
        else            a = *reinterpret_cast<const bf16x8*>(&embM[r0 + lr][32*f + 8*g]);
        #pragma unroll
        for (int c = 0; c < 8; ++c) {
          const float* wp = W1 + (size_t)(ebase + 32*f + 8*g) * H_ + 16*c + lr;
          bf16x8 bb;
          #pragma unroll
          for (int i = 0; i < 8; ++i) bb[i] = f2bf(wp[i * H_]);
          acc[c] = __builtin_amdgcn_mfma_f32_16x16x32_bf16(a, bb, acc[c], 0, 0, 0);
        }
      }
      #pragma unroll
      for (int c = 0; c < 8; ++c) {
        const int col = 16*c + lr;
        #pragma unroll
        for (int rgi = 0; rgi < 4; ++rgi) {
          const int row = r0 + 4*g + rgi;
          if (phase == 0) { if (row < NJ_) jp[row][col] = acc[c][rgi]; }
          else            { if (row < NM_) mp[row][col] = acc[c][rgi] + b1[col]; }
        }
      }
    }
  }
  __syncthreads();

  // ---------------- preload W2 fragments into registers --------------------
  bf16x8 w2f[4][8];
  #pragma unroll
  for (int f = 0; f < 4; ++f) {
    #pragma unroll
    for (int c = 0; c < 8; ++c) {
      const float* wp = W2 + (size_t)(32*f + 8*g) * H_ + 16*c + lr;
      bf16x8 bb;
      #pragma unroll
      for (int i = 0; i < 8; ++i) bb[i] = f2bf(wp[i * H_]);
      w2f[f][c] = bb;
    }
  }
  float b2r[8], w3r[8];
  #pragma unroll
  for (int c = 0; c < 8; ++c) { b2r[c] = b2[16*c + lr]; w3r[c] = W3[16*c + lr]; }
  const float bias3 = b3[0];

  float* __restrict__ outrow = out + (size_t)b * NCOL_ + 1;

  // ---------------- main loop: 125 row-tiles of 16 rows --------------------
  #pragma unroll 1
  for (int t = wave; t < 125; t += 4) {
    const int tp0  = t * 16;
    const int rowr = tp0 + lr;              // this lane's A-row (0..1999)
    const int j = rowr / 40;
    const int m = rowr - j * 40;
    const float* jrow = &jp[j][8*g];
    const float* mrow = &mp[m][8*g];
    bf16x8 afr[4];
    #pragma unroll
    for (int f = 0; f < 4; ++f) {
      const float4 x0 = *reinterpret_cast<const float4*>(jrow + 32*f);
      const float4 x1 = *reinterpret_cast<const float4*>(jrow + 32*f + 4);
      const float4 y0 = *reinterpret_cast<const float4*>(mrow + 32*f);
      const float4 y1 = *reinterpret_cast<const float4*>(mrow + 32*f + 4);
      bf16x8 a;
      a[0] = f2bf(fmaxf(x0.x + y0.x, 0.f));
      a[1] = f2bf(fmaxf(x0.y + y0.y, 0.f));
      a[2] = f2bf(fmaxf(x0.z + y0.z, 0.f));
      a[3] = f2bf(fmaxf(x0.w + y0.w, 0.f));
      a[4] = f2bf(fmaxf(x1.x + y1.x, 0.f));
      a[5] = f2bf(fmaxf(x1.y + y1.y, 0.f));
      a[6] = f2bf(fmaxf(x1.z + y1.z, 0.f));
      a[7] = f2bf(fmaxf(x1.w + y1.w, 0.f));
      afr[f] = a;
    }
    f32x4 acc[8];
    #pragma unroll
    for (int c = 0; c < 8; ++c) acc[c] = f32x4{0.f, 0.f, 0.f, 0.f};
    #pragma unroll
    for (int f = 0; f < 4; ++f) {
      #pragma unroll
      for (int c = 0; c < 8; ++c)
        acc[c] = __builtin_amdgcn_mfma_f32_16x16x32_bf16(afr[f], w2f[f][c], acc[c], 0, 0, 0);
    }
    // epilogue: relu(h2 + b2) . W3, reduce over the 16 col-lanes
    float p0v = 0.f, p1v = 0.f, p2v = 0.f, p3v = 0.f;
    #pragma unroll
    for (int c = 0; c < 8; ++c) {
      p0v += fmaxf(acc[c][0] + b2r[c], 0.f) * w3r[c];
      p1v += fmaxf(acc[c][1] + b2r[c], 0.f) * w3r[c];
      p2v += fmaxf(acc[c][2] + b2r[c], 0.f) * w3r[c];
      p3v += fmaxf(acc[c][3] + b2r[c], 0.f) * w3r[c];
    }
    #pragma unroll
    for (int s = 1; s < 16; s <<= 1) {
      p0v += __shfl_xor(p0v, s);
      p1v += __shfl_xor(p1v, s);
      p2v += __shfl_xor(p2v, s);
      p3v += __shfl_xor(p3v, s);
    }
    if (lr == 0) {
      const int row = tp0 + 4*g;
      outrow[row + 0] = p0v + bias3;
      outrow[row + 1] = p1v + bias3;
      outrow[row + 2] = p2v + bias3;
      outrow[row + 3] = p3v + bias3;
    }
  }

  // ---------------- mask passthrough (int32 bool -> f32) -------------------
  {
    const int* mrow = amask + (size_t)b * NCOL_;
    float* __restrict__ orow = out + (size_t)BS_ * NCOL_ + (size_t)b * NCOL_;
    for (int i = tid; i < NCOL_; i += 256) orow[i] = mrow[i] != 0 ? 1.0f : 0.0f;
  }

  // ---------------- dummy / noop logit --------------------------------------
  if (tid < H_) {
    float s = b1[tid];
    for (int e = 0; e < 2 * E_; ++e) s += dummy[e] * W1[(size_t)e * H_ + tid];
    dtmp[tid] = fmaxf(s, 0.f);
  }
  __syncthreads();
  float nv = 0.f;
  if (tid < H_) {
    float s = b2[tid];
    for (int k = 0; k < H_; ++k) s += dtmp[k] * W2[(size_t)k * H_ + tid];
    nv = fmaxf(s, 0.f) * W3[tid];
  }
  __syncthreads();
  #pragma unroll
  for (int s = 1; s < 64; s <<= 1) nv += __shfl_xor(nv, s);
  if (lane == 0) dtmp[wave] = nv;
  __syncthreads();
  if (tid == 0) out[(size_t)b * NCOL_] = dtmp[0] + dtmp[1] + dtmp[2] + dtmp[3] + bias3;
}

extern "C" void kernel_launch(void* const* d_in, const int* in_sizes, int n_in,
                              void* d_out, int out_size, void* d_ws, size_t ws_size,
                              hipStream_t stream) {
  (void)in_sizes; (void)n_in; (void)d_ws; (void)ws_size; (void)out_size;
  fjsp_fused<<<dim3(BS_), dim3(256), 0, stream>>>(
      (const float*)d_in[0],                 // ops_emb
      (const float*)d_in[1],                 // ma_emb
      (const int*)d_in[2],                   // next_op
      (const int*)d_in[3],                   // action_mask (bool -> int32)
      (const float*)d_in[4],                 // dummy
      (const float*)d_in[5],                 // W1
      (const float*)d_in[6],                 // b1
      (const float*)d_in[7],                 // W2
      (const float*)d_in[8],                 // b2
      (const float*)d_in[9],                 // W3
      (const float*)d_in[10],                // b3
      (float*)d_out);
}

// Round 3
// 50.754 us; speedup vs baseline: 1.0522x; 1.0522x over previous
//
#include <hip/hip_runtime.h>
#include <hip/hip_bf16.h>

#define BS_   256
#define NOPS_ 2000
#define NJ_   50
#define NM_   40
#define E_    128
#define H_    128
#define NCOL_ 2001   // 1 + 50*40

// ws layout (bytes): [0,65536) W1T bf16 [h=128][e=256]
//                    [65536,98304) W2T bf16 [n=128][k=128]
//                    [98304,98308) noop logit f32
#define WS_W2T_OFF  32768   // in ushorts
#define WS_NOOP_OFF 98304   // in bytes

using bf16x8 = __attribute__((ext_vector_type(8))) short;
using f32x4  = __attribute__((ext_vector_type(4))) float;

static __device__ __forceinline__ short f2bf(float f) {
  __hip_bfloat16 h = __float2bfloat16(f);
  return __builtin_bit_cast(short, h);
}

// ---------------------------------------------------------------------------
// prep: transpose+convert W1/W2 to bf16 in ws; compute noop logit once.
// blocks 0-7: W1T[h][e] ; blocks 8-11: W2T[n][k] ; block 12: noop
// ---------------------------------------------------------------------------
__global__ __launch_bounds__(256) void fjsp_prep(
    const float* __restrict__ dummy,
    const float* __restrict__ W1, const float* __restrict__ b1,
    const float* __restrict__ W2, const float* __restrict__ b2,
    const float* __restrict__ W3, const float* __restrict__ b3,
    unsigned short* __restrict__ ws1, unsigned short* __restrict__ ws2,
    float* __restrict__ wsn)
{
  const int blk = blockIdx.x, tid = threadIdx.x;
  if (blk < 8) {
    const int h = tid & 127, esub = tid >> 7, e0 = blk * 32;
    #pragma unroll
    for (int p = 0; p < 16; ++p) {
      const int e = e0 + 2 * p + esub;
      ws1[h * 256 + e] = (unsigned short)f2bf(W1[(size_t)e * H_ + h]);
    }
  } else if (blk < 12) {
    const int n = tid & 127, ksub = tid >> 7, k0 = (blk - 8) * 32;
    #pragma unroll
    for (int p = 0; p < 16; ++p) {
      const int k = k0 + 2 * p + ksub;
      ws2[n * 128 + k] = (unsigned short)f2bf(W2[(size_t)k * H_ + n]);
    }
  } else {
    __shared__ float dtmp[128];
    __shared__ float wsum[2];
    if (tid < H_) {
      float s = b1[tid];
      for (int e = 0; e < 2 * E_; ++e) s += dummy[e] * W1[(size_t)e * H_ + tid];
      dtmp[tid] = fmaxf(s, 0.f);
    }
    __syncthreads();
    float nv = 0.f;
    if (tid < H_) {
      float s = b2[tid];
      for (int k = 0; k < H_; ++k) s += dtmp[k] * W2[(size_t)k * H_ + tid];
      nv = fmaxf(s, 0.f) * W3[tid];
    }
    #pragma unroll
    for (int s = 1; s < 64; s <<= 1) nv += __shfl_xor(nv, s);
    if (tid < 128 && (tid & 63) == 0) wsum[tid >> 6] = nv;
    __syncthreads();
    if (tid == 0) wsn[0] = wsum[0] + wsum[1] + b3[0];
  }
}

// ---------------------------------------------------------------------------
// main: one block (512 thr, 8 waves) per batch element
// ---------------------------------------------------------------------------
__global__ __launch_bounds__(512, 2) void fjsp_main(
    const float* __restrict__ ops_emb,
    const float* __restrict__ ma_emb,
    const int*   __restrict__ next_op,
    const int*   __restrict__ amask,
    const float* __restrict__ b1,
    const float* __restrict__ b2,
    const float* __restrict__ W3,
    const float* __restrict__ b3,
    const unsigned short* __restrict__ ws1,
    const unsigned short* __restrict__ ws2,
    const float* __restrict__ wsn,
    float* __restrict__ out)
{
  const int b    = blockIdx.x;
  const int tid  = threadIdx.x;
  const int lane = tid & 63;
  const int wave = tid >> 6;
  const int g    = lane >> 4;   // 0..3
  const int lr   = lane & 15;   // 0..15

  __shared__ __align__(16) unsigned short embJ[64][136];
  __shared__ __align__(16) unsigned short embM[48][136];
  __shared__ __align__(16) float jp[NJ_][132];
  __shared__ __align__(16) float mp[NM_][132];

  // ---------------- stage embeddings (f32 -> bf16), 8 thr/row --------------
  {
    const int r = tid >> 3, part = tid & 7;   // 16 elems each at part*16
    if (r < NJ_) {
      const int idx = next_op[b * NJ_ + r];
      const float4* p = reinterpret_cast<const float4*>(
          ops_emb + ((size_t)b * NOPS_ + idx) * E_) + part * 4;
      #pragma unroll
      for (int q = 0; q < 4; ++q) {
        const float4 v = p[q];
        const int k = part * 16 + q * 4;
        embJ[r][k+0] = (unsigned short)f2bf(v.x);
        embJ[r][k+1] = (unsigned short)f2bf(v.y);
        embJ[r][k+2] = (unsigned short)f2bf(v.z);
        embJ[r][k+3] = (unsigned short)f2bf(v.w);
      }
    } else {
      #pragma unroll
      for (int q = 0; q < 4; ++q) {
        const int k = part * 16 + q * 4;
        embJ[r][k+0] = 0; embJ[r][k+1] = 0; embJ[r][k+2] = 0; embJ[r][k+3] = 0;
      }
    }
    if (r < 48) {
      if (r < NM_) {
        const float4* p = reinterpret_cast<const float4*>(
            ma_emb + ((size_t)b * NM_ + r) * E_) + part * 4;
        #pragma unroll
        for (int q = 0; q < 4; ++q) {
          const float4 v = p[q];
          const int k = part * 16 + q * 4;
          embM[r][k+0] = (unsigned short)f2bf(v.x);
          embM[r][k+1] = (unsigned short)f2bf(v.y);
          embM[r][k+2] = (unsigned short)f2bf(v.z);
          embM[r][k+3] = (unsigned short)f2bf(v.w);
        }
      } else {
        #pragma unroll
        for (int q = 0; q < 4; ++q) {
          const int k = part * 16 + q * 4;
          embM[r][k+0] = 0; embM[r][k+1] = 0; embM[r][k+2] = 0; embM[r][k+3] = 0;
        }
      }
    }
  }
  __syncthreads();

  // ------- stage A: jp = embJ @ W1[:128] ; mp = embM @ W1[128:] + b1 -------
  // 7 row-tiles across waves 0-6; B-frags coalesced bf16 from ws1
  if (wave < 7) {
    const int phase = (wave < 4) ? 0 : 1;
    const int r0    = (phase ? (wave - 4) : wave) * 16;
    const int ebase = phase ? E_ : 0;
    f32x4 acc[8];
    #pragma unroll
    for (int c = 0; c < 8; ++c) acc[c] = f32x4{0.f, 0.f, 0.f, 0.f};
    #pragma unroll
    for (int f = 0; f < 4; ++f) {
      bf16x8 a;
      if (phase == 0) a = *reinterpret_cast<const bf16x8*>(&embJ[r0 + lr][32*f + 8*g]);
      else            a = *reinterpret_cast<const bf16x8*>(&embM[r0 + lr][32*f + 8*g]);
      #pragma unroll
      for (int c = 0; c < 8; ++c) {
        const bf16x8 bb = *reinterpret_cast<const bf16x8*>(
            ws1 + (size_t)(16*c + lr) * 256 + ebase + 32*f + 8*g);
        acc[c] = __builtin_amdgcn_mfma_f32_16x16x32_bf16(a, bb, acc[c], 0, 0, 0);
      }
    }
    #pragma unroll
    for (int c = 0; c < 8; ++c) {
      const int col = 16*c + lr;
      #pragma unroll
      for (int i = 0; i < 4; ++i) {
        const int row = r0 + 4*g + i;
        if (phase == 0) { if (row < NJ_) jp[row][col] = acc[c][i]; }
        else            { if (row < NM_) mp[row][col] = acc[c][i] + b1[col]; }
      }
    }
  }

  // ---------------- W2 fragments from ws2 (coalesced bf16) -----------------
  bf16x8 w2f[4][8];
  #pragma unroll
  for (int f = 0; f < 4; ++f)
    #pragma unroll
    for (int c = 0; c < 8; ++c)
      w2f[f][c] = *reinterpret_cast<const bf16x8*>(
          ws2 + (size_t)(16*c + lr) * 128 + 32*f + 8*g);
  float b2r[8], w3r[8];
  #pragma unroll
  for (int c = 0; c < 8; ++c) { b2r[c] = b2[16*c + lr]; w3r[c] = W3[16*c + lr]; }
  const float bias3 = b3[0];

  __syncthreads();

  float* __restrict__ outrow = out + (size_t)b * NCOL_ + 1;

  // ---------------- main loop: 125 row-tiles of 16 rows --------------------
  #pragma unroll 1
  for (int t = wave; t < 125; t += 8) {
    const int tp0  = t * 16;
    const int rowr = tp0 + lr;
    const int j = rowr / 40;
    const int m = rowr - j * 40;
    const float* jrow = &jp[j][8*g];
    const float* mrow = &mp[m][8*g];
    bf16x8 afr[4];
    #pragma unroll
    for (int f = 0; f < 4; ++f) {
      const float4 x0 = *reinterpret_cast<const float4*>(jrow + 32*f);
      const float4 x1 = *reinterpret_cast<const float4*>(jrow + 32*f + 4);
      const float4 y0 = *reinterpret_cast<const float4*>(mrow + 32*f);
      const float4 y1 = *reinterpret_cast<const float4*>(mrow + 32*f + 4);
      bf16x8 a;
      a[0] = f2bf(fmaxf(x0.x + y0.x, 0.f));
      a[1] = f2bf(fmaxf(x0.y + y0.y, 0.f));
      a[2] = f2bf(fmaxf(x0.z + y0.z, 0.f));
      a[3] = f2bf(fmaxf(x0.w + y0.w, 0.f));
      a[4] = f2bf(fmaxf(x1.x + y1.x, 0.f));
      a[5] = f2bf(fmaxf(x1.y + y1.y, 0.f));
      a[6] = f2bf(fmaxf(x1.z + y1.z, 0.f));
      a[7] = f2bf(fmaxf(x1.w + y1.w, 0.f));
      afr[f] = a;
    }
    f32x4 acc[8];
    #pragma unroll
    for (int c = 0; c < 8; ++c)
      acc[c] = f32x4{b2r[c], b2r[c], b2r[c], b2r[c]};   // b2 folded into C-init
    #pragma unroll
    for (int f = 0; f < 4; ++f) {
      #pragma unroll
      for (int c = 0; c < 8; ++c)
        acc[c] = __builtin_amdgcn_mfma_f32_16x16x32_bf16(afr[f], w2f[f][c], acc[c], 0, 0, 0);
    }
    float p0v = 0.f, p1v = 0.f, p2v = 0.f, p3v = 0.f;
    #pragma unroll
    for (int c = 0; c < 8; ++c) {
      p0v = fmaf(fmaxf(acc[c][0], 0.f), w3r[c], p0v);
      p1v = fmaf(fmaxf(acc[c][1], 0.f), w3r[c], p1v);
      p2v = fmaf(fmaxf(acc[c][2], 0.f), w3r[c], p2v);
      p3v = fmaf(fmaxf(acc[c][3], 0.f), w3r[c], p3v);
    }
    #pragma unroll
    for (int s = 1; s < 16; s <<= 1) {
      p0v += __shfl_xor(p0v, s);
      p1v += __shfl_xor(p1v, s);
      p2v += __shfl_xor(p2v, s);
      p3v += __shfl_xor(p3v, s);
    }
    if (lr == 0) {
      const int row = tp0 + 4*g;
      outrow[row + 0] = p0v + bias3;
      outrow[row + 1] = p1v + bias3;
      outrow[row + 2] = p2v + bias3;
      outrow[row + 3] = p3v + bias3;
    }
  }

  // ---------------- mask passthrough (int32 bool -> f32) -------------------
  {
    const int* mrow = amask + (size_t)b * NCOL_;
    float* __restrict__ orow = out + (size_t)BS_ * NCOL_ + (size_t)b * NCOL_;
    for (int i = tid; i < NCOL_; i += 512) orow[i] = mrow[i] != 0 ? 1.0f : 0.0f;
  }

  // ---------------- noop logit (precomputed by prep) -----------------------
  if (tid == 0) out[(size_t)b * NCOL_] = wsn[0];
}

extern "C" void kernel_launch(void* const* d_in, const int* in_sizes, int n_in,
                              void* d_out, int out_size, void* d_ws, size_t ws_size,
                              hipStream_t stream) {
  (void)in_sizes; (void)n_in; (void)ws_size; (void)out_size;
  unsigned short* ws1 = (unsigned short*)d_ws;
  unsigned short* ws2 = ws1 + WS_W2T_OFF;
  float*          wsn = (float*)((char*)d_ws + WS_NOOP_OFF);

  fjsp_prep<<<dim3(13), dim3(256), 0, stream>>>(
      (const float*)d_in[4],   // dummy
      (const float*)d_in[5],   // W1
      (const float*)d_in[6],   // b1
      (const float*)d_in[7],   // W2
      (const float*)d_in[8],   // b2
      (const float*)d_in[9],   // W3
      (const float*)d_in[10],  // b3
      ws1, ws2, wsn);

  fjsp_main<<<dim3(BS_), dim3(512), 0, stream>>>(
      (const float*)d_in[0],   // ops_emb
      (const float*)d_in[1],   // ma_emb
      (const int*)d_in[2],     // next_op
      (const int*)d_in[3],     // action_mask (bool -> int32)
      (const float*)d_in[6],   // b1
      (const float*)d_in[8],   // b2
      (const float*)d_in[9],   // W3
      (const float*)d_in[10],  // b3
      ws1, ws2, wsn,
      (float*)d_out);
}